// Round 16
// baseline (34.327 us; speedup 1.0000x reference)
//
#include <hip/hip_runtime.h>
#include <stdint.h>

#define NN   4096
#define NE   131072
#define KIN  512
#define NH   8
#define HF   256
#define SLOPE 0.2f
#define MAXJ 256

typedef __attribute__((ext_vector_type(8))) short bf16x8;
typedef __attribute__((ext_vector_type(4))) float f32x4;

// ws layout: [0,2MB) bitmap | [2,4MB) gbf bf16 | [4MB,+128K) el | +128K er |
//            [4.25MB,+256K) Btbf (W_fc^T bf16)

__device__ __forceinline__ unsigned short f2bf(float x) {  // RTN-even f32->bf16
  unsigned u = __builtin_bit_cast(unsigned, x);
  u += 0x7FFFu + ((u >> 16) & 1u);
  return (unsigned short)(u >> 16);
}
__device__ __forceinline__ float bf2f(unsigned short x) {
  unsigned u = ((unsigned)x) << 16;
  return __builtin_bit_cast(float, u);
}
__device__ __forceinline__ unsigned pack2(float lo, float hi) {
  return (unsigned)f2bf(lo) | ((unsigned)f2bf(hi) << 16);
}

// K1: blocks 0..127 clear bitmap (4 float4/thread); 128..255 W_fc -> B^T bf16
__global__ __launch_bounds__(256) void prep_k(const float* __restrict__ B,
                                              unsigned* __restrict__ bitmap,
                                              unsigned short* __restrict__ Btbf) {
  __shared__ float tile[32][33];
  const int b = blockIdx.x, t = threadIdx.x;
  if (b < 128) {
    float4* p = (float4*)bitmap + (size_t)b * 1024;
#pragma unroll
    for (int it = 0; it < 4; ++it)
      p[it * 256 + t] = make_float4(0.f, 0.f, 0.f, 0.f);
  } else {
    int bb = b - 128;
    int k0 = (bb >> 3) * 32, n0 = (bb & 7) * 32;
    int lr = t >> 3, lc = (t & 7) * 4;
    float4 v = *(const float4*)&B[(size_t)(k0 + lr) * HF + n0 + lc];
    tile[lr][lc] = v.x; tile[lr][lc + 1] = v.y; tile[lr][lc + 2] = v.z; tile[lr][lc + 3] = v.w;
    __syncthreads();
    ushort4 o;
    o.x = f2bf(tile[lc + 0][lr]); o.y = f2bf(tile[lc + 1][lr]);
    o.z = f2bf(tile[lc + 2][lr]); o.w = f2bf(tile[lc + 3][lr]);
    *(ushort4*)&Btbf[(size_t)(n0 + lr) * KIN + k0 + lc] = o;
  }
}

// K2: blocks 0..527 = build_adj scatter (FIRST: short atomic blocks ramp while
//     gemm blocks stream behind). Blocks 528..783 = 64x64 MFMA GEMM tiles
//     (64 M-tiles x 4 col-tiles; 4 waves each own a 32x32 quadrant = 1 head's
//     full f-range). BK=64 dbuf; A reg-staged (f32->bf16 pack, swizzled
//     ds_write), B via global_load_lds (pre-swizzled source, rule #21).
//     8 MFMA/wave/barrier (2x R15's density). Per-element K-order preserved
//     -> bitwise-identical acc. In-wave el/er epilogue.
__global__ __launch_bounds__(256) void gemm_adj_k(const float* __restrict__ h,
                                                  const unsigned short* __restrict__ Bt,
                                                  const float* __restrict__ Wa,
                                                  unsigned short* __restrict__ gbf,
                                                  float* __restrict__ el,
                                                  float* __restrict__ er,
                                                  const int* __restrict__ ei,
                                                  const float* __restrict__ mask,
                                                  unsigned* __restrict__ bitmap) {
  __shared__ unsigned short smem[2][8192];  // per buf: A[64][64]@0, B[64][64]@4096
  const int bx = blockIdx.x, t = threadIdx.x;
  if (bx < 528) {  // ---- build_adj: NE+NN = 135168 = 528*256 exactly ----
    int k = bx * 256 + t;
    int s, d; float m;
    if (k < NE) { s = ei[k]; d = ei[NE + k]; m = mask[k]; }
    else        { s = k - NE; d = s; m = 1.0f; }   // diagonal forced to 1
    if (m != 0.0f) atomicOr(&bitmap[s * 128 + (d >> 5)], 1u << (d & 31));
    return;
  }
  // ---- gemm: 64x64 tile; wave (wr,wc) owns rows wr*32..+32, cols wc*32..+32 ----
  const int g = bx - 528;
  const int gx = g & 63, gy = g >> 6;             // 64 M-tiles x 4 col-tiles
  const int row0 = gx * 64, col0 = gy * 64;
  const int w = t >> 6, l = t & 63;
  const int wr = w >> 1, wc = w & 1;

  // A staging: thread t handles rows r0=t>>3 and r1=32+r0, chunk c=t&7.
  // LDS slot (row,chunk) holds logical k-chunk (chunk ^ (row&7)); write swizzled.
  const int r0 = t >> 3, c0 = t & 7;
  const int aoff0 = r0 * 64 + ((c0 ^ (r0 & 7)) << 3);       // ushort offset
  const int aoff1 = aoff0 + 2048;                           // r1 = r0+32, same key
  const float* gA0 = &h[(size_t)(row0 + r0) * KIN + c0 * 8];
  const float* gA1 = gA0 + 32 * KIN;
  // B staging: wave w stages rows (8w + l>>3) and (32+8w + l>>3); dest linear,
  // source chunk pre-swizzled: key = row&7 = l>>3.
  const int sch = (l & 7) ^ (l >> 3);
  const unsigned short* gB0 = &Bt[(size_t)(col0 + (w << 3) + (l >> 3)) * KIN + sch * 8];
  const unsigned short* gB1 = gB0 + 32 * KIN;

#define BSTAGE(bf, ks)                                                                            \
  do {                                                                                            \
    __builtin_amdgcn_global_load_lds(                                                             \
        (const __attribute__((address_space(1))) unsigned int*)(gB0 + (size_t)(ks) * 64),         \
        (__attribute__((address_space(3))) unsigned int*)(&smem[bf][4096 + w * 512]), 16, 0, 0);  \
    __builtin_amdgcn_global_load_lds(                                                             \
        (const __attribute__((address_space(1))) unsigned int*)(gB1 + (size_t)(ks) * 64),         \
        (__attribute__((address_space(3))) unsigned int*)(&smem[bf][6144 + w * 512]), 16, 0, 0);  \
  } while (0)

  f32x4 acc00 = {}, acc01 = {}, acc10 = {}, acc11 = {};
  {
    float4 v00 = *(const float4*)(gA0), v01 = *(const float4*)(gA0 + 4);
    float4 v10 = *(const float4*)(gA1), v11 = *(const float4*)(gA1 + 4);
    BSTAGE(0, 0);
    uint4 w0 = {pack2(v00.x, v00.y), pack2(v00.z, v00.w),
                pack2(v01.x, v01.y), pack2(v01.z, v01.w)};
    uint4 w1 = {pack2(v10.x, v10.y), pack2(v10.z, v10.w),
                pack2(v11.x, v11.y), pack2(v11.z, v11.w)};
    *(uint4*)&smem[0][aoff0] = w0;
    *(uint4*)&smem[0][aoff1] = w1;
  }
  __syncthreads();

  const int lrow = l & 15, kg = l >> 4;
  const int ar0 = wr * 32 + lrow, ar1 = ar0 + 16;
  const int br0 = wc * 32 + lrow, br1 = br0 + 16;
  for (int ks = 0; ks < 8; ++ks) {
    const int bf = ks & 1;
    float4 v00, v01, v10, v11;
    if (ks < 7) {                            // issue next-step A loads early (T14)
      v00 = *(const float4*)(gA0 + (ks + 1) * 64);
      v01 = *(const float4*)(gA0 + (ks + 1) * 64 + 4);
      v10 = *(const float4*)(gA1 + (ks + 1) * 64);
      v11 = *(const float4*)(gA1 + (ks + 1) * 64 + 4);
      BSTAGE(bf ^ 1, ks + 1);
    }
    bf16x8 a00 = *(const bf16x8*)&smem[bf][ar0 * 64 + ((kg ^ (ar0 & 7)) << 3)];
    bf16x8 a01 = *(const bf16x8*)&smem[bf][ar0 * 64 + (((4 + kg) ^ (ar0 & 7)) << 3)];
    bf16x8 a10 = *(const bf16x8*)&smem[bf][ar1 * 64 + ((kg ^ (ar1 & 7)) << 3)];
    bf16x8 a11 = *(const bf16x8*)&smem[bf][ar1 * 64 + (((4 + kg) ^ (ar1 & 7)) << 3)];
    bf16x8 b00 = *(const bf16x8*)&smem[bf][4096 + br0 * 64 + ((kg ^ (br0 & 7)) << 3)];
    bf16x8 b01 = *(const bf16x8*)&smem[bf][4096 + br0 * 64 + (((4 + kg) ^ (br0 & 7)) << 3)];
    bf16x8 b10 = *(const bf16x8*)&smem[bf][4096 + br1 * 64 + ((kg ^ (br1 & 7)) << 3)];
    bf16x8 b11 = *(const bf16x8*)&smem[bf][4096 + br1 * 64 + (((4 + kg) ^ (br1 & 7)) << 3)];
    acc00 = __builtin_amdgcn_mfma_f32_16x16x32_bf16(a00, b00, acc00, 0, 0, 0);
    acc00 = __builtin_amdgcn_mfma_f32_16x16x32_bf16(a01, b01, acc00, 0, 0, 0);
    acc01 = __builtin_amdgcn_mfma_f32_16x16x32_bf16(a00, b10, acc01, 0, 0, 0);
    acc01 = __builtin_amdgcn_mfma_f32_16x16x32_bf16(a01, b11, acc01, 0, 0, 0);
    acc10 = __builtin_amdgcn_mfma_f32_16x16x32_bf16(a10, b00, acc10, 0, 0, 0);
    acc10 = __builtin_amdgcn_mfma_f32_16x16x32_bf16(a11, b01, acc10, 0, 0, 0);
    acc11 = __builtin_amdgcn_mfma_f32_16x16x32_bf16(a10, b10, acc11, 0, 0, 0);
    acc11 = __builtin_amdgcn_mfma_f32_16x16x32_bf16(a11, b11, acc11, 0, 0, 0);
    if (ks < 7) {                            // write-late into the other buffer
      uint4 w0 = {pack2(v00.x, v00.y), pack2(v00.z, v00.w),
                  pack2(v01.x, v01.y), pack2(v01.z, v01.w)};
      uint4 w1 = {pack2(v10.x, v10.y), pack2(v10.z, v10.w),
                  pack2(v11.x, v11.y), pack2(v11.z, v11.w)};
      *(uint4*)&smem[bf ^ 1][aoff0] = w0;
      *(uint4*)&smem[bf ^ 1][aoff1] = w1;
    }
    __syncthreads();
  }
#undef BSTAGE

  // C/D: col=lane&15, row=(lane>>4)*4+q  [m89-verified]
  const int crow = (l >> 4) * 4, ccol = l & 15;
#pragma unroll
  for (int q = 0; q < 4; ++q) {
    int grA = row0 + wr * 32 + crow + q;
    int grB = grA + 16;
    int gcA = col0 + wc * 32 + ccol;
    gbf[(size_t)grA * HF + gcA]      = f2bf(acc00[q]);
    gbf[(size_t)grA * HF + gcA + 16] = f2bf(acc01[q]);
    gbf[(size_t)grB * HF + gcA]      = f2bf(acc10[q]);
    gbf[(size_t)grB * HF + gcA + 16] = f2bf(acc11[q]);
  }

  // fused el/er: wave covers head (gy*2+wc)'s FULL f range: f = cfrag*16 + ccol
  const int head = (gy << 1) + wc;
  const float wal0 = Wa[ccol],      wal1 = Wa[16 + ccol];
  const float war0 = Wa[32 + ccol], war1 = Wa[48 + ccol];
#pragma unroll
  for (int q = 0; q < 4; ++q) {
    float pel0 = acc00[q] * wal0 + acc01[q] * wal1;
    float per0 = acc00[q] * war0 + acc01[q] * war1;
    float pel1 = acc10[q] * wal0 + acc11[q] * wal1;
    float per1 = acc10[q] * war0 + acc11[q] * war1;
#pragma unroll
    for (int m = 8; m >= 1; m >>= 1) {
      pel0 += __shfl_xor(pel0, m); per0 += __shfl_xor(per0, m);
      pel1 += __shfl_xor(pel1, m); per1 += __shfl_xor(per1, m);
    }
    if (ccol == 0) {
      int rA = row0 + wr * 32 + crow + q;
      el[rA * NH + head] = pel0;
      er[rA * NH + head] = per0;
      el[(rA + 16) * NH + head] = pel1;
      er[(rA + 16) * NH + head] = per1;
    }
  }
}

// K3: one WAVE per row, 8 rows/block (512 threads). Lane l owns output elems
// [l*4, l*4+4) (head l>>3). Wave-local bitmap expand; 4-way MLP gather loop.
__global__ __launch_bounds__(512) void attn_k(const unsigned* __restrict__ bitmap,
                                              const unsigned short* __restrict__ gbf,
                                              const float* __restrict__ el_,
                                              const float* __restrict__ er_,
                                              float* __restrict__ out) {
  __shared__ unsigned short jl[8][MAXJ];     // 4KB
  const int t = threadIdx.x, wv = t >> 6, l = t & 63;
  const int i = blockIdx.x * 8 + wv;

  unsigned w0 = bitmap[i * 128 + l];
  unsigned w1 = bitmap[i * 128 + 64 + l];
  int cnt = __popc(w0) + __popc(w1);
  int incl = cnt;
#pragma unroll
  for (int d = 1; d < 64; d <<= 1) {
    int u = __shfl_up(incl, d);
    if (l >= d) incl += u;
  }
  int total = __shfl(incl, 63);
  if (total > MAXJ) total = MAXJ;
  int off = incl - cnt;
  unsigned short* J = jl[wv];
  while (w0) {
    int b = __ffs(w0) - 1;
    if (off < MAXJ) J[off] = (unsigned short)(l * 32 + b);
    ++off; w0 &= w0 - 1;
  }
  while (w1) {
    int b = __ffs(w1) - 1;
    if (off < MAXJ) J[off] = (unsigned short)((64 + l) * 32 + b);
    ++off; w1 &= w1 - 1;
  }
  __syncthreads();

  const int hh = l >> 3;
  const float elh = el_[i * NH + hh];
  const unsigned short* gp = gbf + (size_t)l * 4;
  f32x4 accA = {}, accB = {};
  float den0 = 0.f, den1 = 0.f;
  int k = 0;
  for (; k + 4 <= total; k += 4) {           // 4-way MLP: 4 rows + 4 er in flight
    int j0 = J[k], j1 = J[k + 1], j2 = J[k + 2], j3 = J[k + 3];
    float e0 = elh + er_[j0 * NH + hh];
    float e1 = elh + er_[j1 * NH + hh];
    float e2 = elh + er_[j2 * NH + hh];
    float e3 = elh + er_[j3 * NH + hh];
    ushort4 g0 = *(const ushort4*)(gp + (size_t)j0 * HF);
    ushort4 g1 = *(const ushort4*)(gp + (size_t)j1 * HF);
    ushort4 g2 = *(const ushort4*)(gp + (size_t)j2 * HF);
    ushort4 g3 = *(const ushort4*)(gp + (size_t)j3 * HF);
    float l0 = e0 > 0.f ? e0 : SLOPE * e0;
    float l1 = e1 > 0.f ? e1 : SLOPE * e1;
    float l2 = e2 > 0.f ? e2 : SLOPE * e2;
    float l3 = e3 > 0.f ? e3 : SLOPE * e3;
    float wg0 = __expf(l0), wg1 = __expf(l1), wg2 = __expf(l2), wg3 = __expf(l3);
    den0 += wg0 + wg2; den1 += wg1 + wg3;
    accA[0] += wg0 * bf2f(g0.x); accB[0] += wg1 * bf2f(g1.x);
    accA[1] += wg0 * bf2f(g0.y); accB[1] += wg1 * bf2f(g1.y);
    accA[2] += wg0 * bf2f(g0.z); accB[2] += wg1 * bf2f(g1.z);
    accA[3] += wg0 * bf2f(g0.w); accB[3] += wg1 * bf2f(g1.w);
    accA[0] += wg2 * bf2f(g2.x); accB[0] += wg3 * bf2f(g3.x);
    accA[1] += wg2 * bf2f(g2.y); accB[1] += wg3 * bf2f(g3.y);
    accA[2] += wg2 * bf2f(g2.z); accB[2] += wg3 * bf2f(g3.z);
    accA[3] += wg2 * bf2f(g2.w); accB[3] += wg3 * bf2f(g3.w);
  }
  for (; k < total; ++k) {
    int j0 = J[k];
    float e0 = elh + er_[j0 * NH + hh];
    float l0 = e0 > 0.f ? e0 : SLOPE * e0;
    float wg0 = __expf(l0);
    ushort4 g0 = *(const ushort4*)(gp + (size_t)j0 * HF);
    den0 += wg0;
    accA[0] += wg0 * bf2f(g0.x); accA[1] += wg0 * bf2f(g0.y);
    accA[2] += wg0 * bf2f(g0.z); accA[3] += wg0 * bf2f(g0.w);
  }
  float inv = 1.f / (den0 + den1);
  float4 o = make_float4((accA[0] + accB[0]) * inv, (accA[1] + accB[1]) * inv,
                         (accA[2] + accB[2]) * inv, (accA[3] + accB[3]) * inv);
  *(float4*)&out[(size_t)i * HF + l * 4] = o;
}

extern "C" void kernel_launch(void* const* d_in, const int* in_sizes, int n_in,
                              void* d_out, int out_size, void* d_ws, size_t ws_size,
                              hipStream_t stream) {
  const float* h      = (const float*)d_in[0];
  const int*   ei     = (const int*)d_in[1];
  const float* mask   = (const float*)d_in[2];
  const float* W_fc   = (const float*)d_in[3];
  const float* W_attn = (const float*)d_in[4];
  float* out = (float*)d_out;

  char* ws = (char*)d_ws;
  unsigned* bitmap      = (unsigned*)ws;                                          // 2 MB
  unsigned short* gbf   = (unsigned short*)(ws + (size_t)2 * 1024 * 1024);        // 2 MB
  float* el             = (float*)(ws + (size_t)4 * 1024 * 1024);                 // 128 KB
  float* er             = (float*)(ws + (size_t)4 * 1024 * 1024 + 128 * 1024);    // 128 KB
  unsigned short* Btbf  = (unsigned short*)(ws + (size_t)4 * 1024 * 1024 + 256 * 1024);  // 256 KB

  prep_k<<<256, 256, 0, stream>>>(W_fc, bitmap, Btbf);
  gemm_adj_k<<<528 + 256, 256, 0, stream>>>(h, Btbf, W_attn, gbf, el, er, ei, mask, bitmap);
  attn_k<<<NN / 8, 512, 0, stream>>>(bitmap, gbf, el, er, out);
}

// Round 17
// 33.836 us; speedup vs baseline: 1.0145x; 1.0145x over previous
//
#include <hip/hip_runtime.h>
#include <stdint.h>

#define NN   4096
#define NE   131072
#define KIN  512
#define NH   8
#define HF   256
#define SLOPE 0.2f
#define MAXJ 256

typedef __attribute__((ext_vector_type(8))) short bf16x8;
typedef __attribute__((ext_vector_type(4))) float f32x4;

// ws layout: [0,2MB) bitmap | [2,4MB) gbf bf16 | [4MB,+128K) el | +128K er |
//            [4.25MB,+256K) Btbf (W_fc^T bf16)

__device__ __forceinline__ unsigned short f2bf(float x) {  // RTN-even f32->bf16
  unsigned u = __builtin_bit_cast(unsigned, x);
  u += 0x7FFFu + ((u >> 16) & 1u);
  return (unsigned short)(u >> 16);
}
__device__ __forceinline__ float bf2f(unsigned short x) {
  unsigned u = ((unsigned)x) << 16;
  return __builtin_bit_cast(float, u);
}
__device__ __forceinline__ unsigned pack2(float lo, float hi) {
  return (unsigned)f2bf(lo) | ((unsigned)f2bf(hi) << 16);
}

// K1: blocks 0..127 clear bitmap (4 float4/thread); 128..255 W_fc -> B^T bf16
__global__ __launch_bounds__(256) void prep_k(const float* __restrict__ B,
                                              unsigned* __restrict__ bitmap,
                                              unsigned short* __restrict__ Btbf) {
  __shared__ float tile[32][33];
  const int b = blockIdx.x, t = threadIdx.x;
  if (b < 128) {
    float4* p = (float4*)bitmap + (size_t)b * 1024;
#pragma unroll
    for (int it = 0; it < 4; ++it)
      p[it * 256 + t] = make_float4(0.f, 0.f, 0.f, 0.f);
  } else {
    int bb = b - 128;
    int k0 = (bb >> 3) * 32, n0 = (bb & 7) * 32;
    int lr = t >> 3, lc = (t & 7) * 4;
    float4 v = *(const float4*)&B[(size_t)(k0 + lr) * HF + n0 + lc];
    tile[lr][lc] = v.x; tile[lr][lc + 1] = v.y; tile[lr][lc + 2] = v.z; tile[lr][lc + 3] = v.w;
    __syncthreads();
    ushort4 o;
    o.x = f2bf(tile[lc + 0][lr]); o.y = f2bf(tile[lc + 1][lr]);
    o.z = f2bf(tile[lc + 2][lr]); o.w = f2bf(tile[lc + 3][lr]);
    *(ushort4*)&Btbf[(size_t)(n0 + lr) * KIN + k0 + lc] = o;
  }
}

// K2: blocks 0..527 = build_adj scatter (short atomic blocks ramp first).
//     Blocks 528..1039 = 32x64 MFMA GEMM tiles (128 M x 4 col-tiles = 2 heads),
//     [R15-proven structure]. XCD-aware mapping (T1): q=bx-528, xcd=q%8;
//     gx = (q&7)+(q>>5)*8, gy = (q>>3)&3 puts the 4 blocks sharing an A-slice
//     (same gx) at q,q+8,q+16,q+24 -> SAME XCD -> A-slice hits its L2 once.
__global__ __launch_bounds__(256) void gemm_adj_k(const float* __restrict__ h,
                                                  const unsigned short* __restrict__ Bt,
                                                  const float* __restrict__ Wa,
                                                  unsigned short* __restrict__ gbf,
                                                  float* __restrict__ el,
                                                  float* __restrict__ er,
                                                  const int* __restrict__ ei,
                                                  const float* __restrict__ mask,
                                                  unsigned* __restrict__ bitmap) {
  __shared__ unsigned short smem[2][6144];  // per buf: A[32][64]@0, B[64][64]@2048
  const int bx = blockIdx.x, t = threadIdx.x;
  if (bx < 528) {  // ---- build_adj: NE+NN = 135168 = 528*256 exactly ----
    int k = bx * 256 + t;
    int s, d; float m;
    if (k < NE) { s = ei[k]; d = ei[NE + k]; m = mask[k]; }
    else        { s = k - NE; d = s; m = 1.0f; }   // diagonal forced to 1
    if (m != 0.0f) atomicOr(&bitmap[s * 128 + (d >> 5)], 1u << (d & 31));
    return;
  }
  // ---- gemm: 32x64 tile; gy*2+wc selects the head ----
  const int q  = bx - 528;                        // 0..511, xcd = q%8
  const int gx = (q & 7) + ((q >> 5) << 3);       // same-gx blocks -> same XCD
  const int gy = (q >> 3) & 3;
  const int row0 = gx * 32, col0 = gy * 64;
  const int w = t >> 6, l = t & 63;
  const int wr = w >> 1, wc = w & 1;              // wave: rows wr*16..+16, cols wc*32..+32

  const int srow = t >> 3;                        // A stage: row 0..31, chunk t&7
  const int sc   = l & 7;
  const int aoff = srow * 64 + (((t & 7) ^ (srow & 7)) << 3);
  const float* gA = &h[(size_t)(row0 + srow) * KIN + (t & 7) * 8];
  // B stage: wave w, lane l -> rows (8w + l>>3) and (32 + 8w + l>>3); key (row&7) invariant +32
  const int bsrow = (w << 3) + (l >> 3);
  const int schB  = sc ^ (bsrow & 7);
  const unsigned short* gB0 = &Bt[(size_t)(col0 + bsrow) * KIN + schB * 8];
  const unsigned short* gB1 = &Bt[(size_t)(col0 + 32 + bsrow) * KIN + schB * 8];

#define BSTAGE(bf, ks)                                                                            \
  do {                                                                                            \
    __builtin_amdgcn_global_load_lds(                                                             \
        (const __attribute__((address_space(1))) unsigned int*)(gB0 + (size_t)(ks) * 64),         \
        (__attribute__((address_space(3))) unsigned int*)(&smem[bf][2048 + w * 512]), 16, 0, 0);  \
    __builtin_amdgcn_global_load_lds(                                                             \
        (const __attribute__((address_space(1))) unsigned int*)(gB1 + (size_t)(ks) * 64),         \
        (__attribute__((address_space(3))) unsigned int*)(&smem[bf][4096 + w * 512]), 16, 0, 0);  \
  } while (0)

  f32x4 acc0 = {}, acc1 = {};                     // col-frags wc*32+0..16, +16..32
  {
    float4 va0 = *(const float4*)(gA);
    float4 va1 = *(const float4*)(gA + 4);
    BSTAGE(0, 0);
    uint4 w4 = {pack2(va0.x, va0.y), pack2(va0.z, va0.w),
                pack2(va1.x, va1.y), pack2(va1.z, va1.w)};
    *(uint4*)&smem[0][aoff] = w4;
  }
  __syncthreads();

  const int lrow = l & 15, kg = l >> 4;
  const int ar  = wr * 16 + lrow;
  const int br0 = wc * 32 + lrow, br1 = wc * 32 + 16 + lrow;
  for (int ks = 0; ks < 8; ++ks) {
    const int bf = ks & 1;
    float4 na0, na1;
    if (ks < 7) {                                 // issue next-step A loads early (T14)
      na0 = *(const float4*)(gA + (ks + 1) * 64);
      na1 = *(const float4*)(gA + (ks + 1) * 64 + 4);
      BSTAGE(bf ^ 1, ks + 1);
    }
    bf16x8 a0 = *(const bf16x8*)&smem[bf][ar * 64 + ((kg ^ (ar & 7)) << 3)];
    bf16x8 a1 = *(const bf16x8*)&smem[bf][ar * 64 + (((4 + kg) ^ (ar & 7)) << 3)];
    bf16x8 b00 = *(const bf16x8*)&smem[bf][2048 + br0 * 64 + ((kg ^ (br0 & 7)) << 3)];
    bf16x8 b01 = *(const bf16x8*)&smem[bf][2048 + br0 * 64 + (((4 + kg) ^ (br0 & 7)) << 3)];
    bf16x8 b10 = *(const bf16x8*)&smem[bf][2048 + br1 * 64 + ((kg ^ (br1 & 7)) << 3)];
    bf16x8 b11 = *(const bf16x8*)&smem[bf][2048 + br1 * 64 + (((4 + kg) ^ (br1 & 7)) << 3)];
    acc0 = __builtin_amdgcn_mfma_f32_16x16x32_bf16(a0, b00, acc0, 0, 0, 0);
    acc0 = __builtin_amdgcn_mfma_f32_16x16x32_bf16(a1, b01, acc0, 0, 0, 0);
    acc1 = __builtin_amdgcn_mfma_f32_16x16x32_bf16(a0, b10, acc1, 0, 0, 0);
    acc1 = __builtin_amdgcn_mfma_f32_16x16x32_bf16(a1, b11, acc1, 0, 0, 0);
    if (ks < 7) {                                 // write-late into the other buffer
      uint4 w4 = {pack2(na0.x, na0.y), pack2(na0.z, na0.w),
                  pack2(na1.x, na1.y), pack2(na1.z, na1.w)};
      *(uint4*)&smem[bf ^ 1][aoff] = w4;
    }
    __syncthreads();
  }
#undef BSTAGE

  // C/D: col=lane&15, row=(lane>>4)*4+q  [m89-verified]
  const int crow = (l >> 4) * 4, ccol = l & 15;
  const int gr0 = row0 + wr * 16 + crow;
  const int gc0 = col0 + wc * 32 + ccol, gc1 = gc0 + 16;
#pragma unroll
  for (int qq = 0; qq < 4; ++qq) {
    gbf[(size_t)(gr0 + qq) * HF + gc0] = f2bf(acc0[qq]);
    gbf[(size_t)(gr0 + qq) * HF + gc1] = f2bf(acc1[qq]);
  }

  // fused el/er: wave covers head (gy*2+wc)'s FULL f range: f = cfrag*16 + ccol
  const int head = (gy << 1) + wc;
  const float wal0 = Wa[ccol],      wal1 = Wa[16 + ccol];
  const float war0 = Wa[32 + ccol], war1 = Wa[48 + ccol];
#pragma unroll
  for (int qq = 0; qq < 4; ++qq) {
    float pel = acc0[qq] * wal0 + acc1[qq] * wal1;
    float per = acc0[qq] * war0 + acc1[qq] * war1;
#pragma unroll
    for (int m = 8; m >= 1; m >>= 1) { pel += __shfl_xor(pel, m); per += __shfl_xor(per, m); }
    if (ccol == 0) {
      el[(gr0 + qq) * NH + head] = pel;
      er[(gr0 + qq) * NH + head] = per;
    }
  }
}

// K3: one WAVE per row, 8 rows/block (512 threads). Lane l owns output elems
// [l*4, l*4+4) (head l>>3). Wave-local bitmap expand; 4-way MLP gather loop.
__global__ __launch_bounds__(512) void attn_k(const unsigned* __restrict__ bitmap,
                                              const unsigned short* __restrict__ gbf,
                                              const float* __restrict__ el_,
                                              const float* __restrict__ er_,
                                              float* __restrict__ out) {
  __shared__ unsigned short jl[8][MAXJ];     // 4KB
  const int t = threadIdx.x, wv = t >> 6, l = t & 63;
  const int i = blockIdx.x * 8 + wv;

  unsigned w0 = bitmap[i * 128 + l];
  unsigned w1 = bitmap[i * 128 + 64 + l];
  int cnt = __popc(w0) + __popc(w1);
  int incl = cnt;
#pragma unroll
  for (int d = 1; d < 64; d <<= 1) {
    int u = __shfl_up(incl, d);
    if (l >= d) incl += u;
  }
  int total = __shfl(incl, 63);
  if (total > MAXJ) total = MAXJ;
  int off = incl - cnt;
  unsigned short* J = jl[wv];
  while (w0) {
    int b = __ffs(w0) - 1;
    if (off < MAXJ) J[off] = (unsigned short)(l * 32 + b);
    ++off; w0 &= w0 - 1;
  }
  while (w1) {
    int b = __ffs(w1) - 1;
    if (off < MAXJ) J[off] = (unsigned short)((64 + l) * 32 + b);
    ++off; w1 &= w1 - 1;
  }
  __syncthreads();

  const int hh = l >> 3;
  const float elh = el_[i * NH + hh];
  const unsigned short* gp = gbf + (size_t)l * 4;
  f32x4 accA = {}, accB = {};
  float den0 = 0.f, den1 = 0.f;
  int k = 0;
  for (; k + 4 <= total; k += 4) {           // 4-way MLP: 4 rows + 4 er in flight
    int j0 = J[k], j1 = J[k + 1], j2 = J[k + 2], j3 = J[k + 3];
    float e0 = elh + er_[j0 * NH + hh];
    float e1 = elh + er_[j1 * NH + hh];
    float e2 = elh + er_[j2 * NH + hh];
    float e3 = elh + er_[j3 * NH + hh];
    ushort4 g0 = *(const ushort4*)(gp + (size_t)j0 * HF);
    ushort4 g1 = *(const ushort4*)(gp + (size_t)j1 * HF);
    ushort4 g2 = *(const ushort4*)(gp + (size_t)j2 * HF);
    ushort4 g3 = *(const ushort4*)(gp + (size_t)j3 * HF);
    float l0 = e0 > 0.f ? e0 : SLOPE * e0;
    float l1 = e1 > 0.f ? e1 : SLOPE * e1;
    float l2 = e2 > 0.f ? e2 : SLOPE * e2;
    float l3 = e3 > 0.f ? e3 : SLOPE * e3;
    float wg0 = __expf(l0), wg1 = __expf(l1), wg2 = __expf(l2), wg3 = __expf(l3);
    den0 += wg0 + wg2; den1 += wg1 + wg3;
    accA[0] += wg0 * bf2f(g0.x); accB[0] += wg1 * bf2f(g1.x);
    accA[1] += wg0 * bf2f(g0.y); accB[1] += wg1 * bf2f(g1.y);
    accA[2] += wg0 * bf2f(g0.z); accB[2] += wg1 * bf2f(g1.z);
    accA[3] += wg0 * bf2f(g0.w); accB[3] += wg1 * bf2f(g1.w);
    accA[0] += wg2 * bf2f(g2.x); accB[0] += wg3 * bf2f(g3.x);
    accA[1] += wg2 * bf2f(g2.y); accB[1] += wg3 * bf2f(g3.y);
    accA[2] += wg2 * bf2f(g2.z); accB[2] += wg3 * bf2f(g3.z);
    accA[3] += wg2 * bf2f(g2.w); accB[3] += wg3 * bf2f(g3.w);
  }
  for (; k < total; ++k) {
    int j0 = J[k];
    float e0 = elh + er_[j0 * NH + hh];
    float l0 = e0 > 0.f ? e0 : SLOPE * e0;
    float wg0 = __expf(l0);
    ushort4 g0 = *(const ushort4*)(gp + (size_t)j0 * HF);
    den0 += wg0;
    accA[0] += wg0 * bf2f(g0.x); accA[1] += wg0 * bf2f(g0.y);
    accA[2] += wg0 * bf2f(g0.z); accA[3] += wg0 * bf2f(g0.w);
  }
  float inv = 1.f / (den0 + den1);
  float4 o = make_float4((accA[0] + accB[0]) * inv, (accA[1] + accB[1]) * inv,
                         (accA[2] + accB[2]) * inv, (accA[3] + accB[3]) * inv);
  *(float4*)&out[(size_t)i * HF + l * 4] = o;
}

extern "C" void kernel_launch(void* const* d_in, const int* in_sizes, int n_in,
                              void* d_out, int out_size, void* d_ws, size_t ws_size,
                              hipStream_t stream) {
  const float* h      = (const float*)d_in[0];
  const int*   ei     = (const int*)d_in[1];
  const float* mask   = (const float*)d_in[2];
  const float* W_fc   = (const float*)d_in[3];
  const float* W_attn = (const float*)d_in[4];
  float* out = (float*)d_out;

  char* ws = (char*)d_ws;
  unsigned* bitmap      = (unsigned*)ws;                                          // 2 MB
  unsigned short* gbf   = (unsigned short*)(ws + (size_t)2 * 1024 * 1024);        // 2 MB
  float* el             = (float*)(ws + (size_t)4 * 1024 * 1024);                 // 128 KB
  float* er             = (float*)(ws + (size_t)4 * 1024 * 1024 + 128 * 1024);    // 128 KB
  unsigned short* Btbf  = (unsigned short*)(ws + (size_t)4 * 1024 * 1024 + 256 * 1024);  // 256 KB

  prep_k<<<256, 256, 0, stream>>>(W_fc, bitmap, Btbf);
  gemm_adj_k<<<528 + 512, 256, 0, stream>>>(h, Btbf, W_attn, gbf, el, er, ei, mask, bitmap);
  attn_k<<<NN / 8, 512, 0, stream>>>(bitmap, gbf, el, er, out);
}

// Round 18
// 33.004 us; speedup vs baseline: 1.0401x; 1.0252x over previous
//
#include <hip/hip_runtime.h>
#include <stdint.h>

#define NN   4096
#define NE   131072
#define KIN  512
#define NH   8
#define HF   256
#define SLOPE 0.2f
#define MAXJ 256

typedef __attribute__((ext_vector_type(8))) short bf16x8;
typedef __attribute__((ext_vector_type(4))) float f32x4;

// ws layout: [0,2MB) bitmap | [2,4MB) gbf bf16 | [4MB,+128K) el | +128K er |
//            [4.25MB,+256K) Btbf (W_fc^T bf16)

__device__ __forceinline__ unsigned short f2bf(float x) {  // RTN-even f32->bf16
  unsigned u = __builtin_bit_cast(unsigned, x);
  u += 0x7FFFu + ((u >> 16) & 1u);
  return (unsigned short)(u >> 16);
}
__device__ __forceinline__ float bf2f(unsigned short x) {
  unsigned u = ((unsigned)x) << 16;
  return __builtin_bit_cast(float, u);
}
__device__ __forceinline__ unsigned pack2(float lo, float hi) {
  return (unsigned)f2bf(lo) | ((unsigned)f2bf(hi) << 16);
}

// K1: blocks 0..127 clear bitmap (4 float4/thread); 128..255 W_fc -> B^T bf16
__global__ __launch_bounds__(256) void prep_k(const float* __restrict__ B,
                                              unsigned* __restrict__ bitmap,
                                              unsigned short* __restrict__ Btbf) {
  __shared__ float tile[32][33];
  const int b = blockIdx.x, t = threadIdx.x;
  if (b < 128) {
    float4* p = (float4*)bitmap + (size_t)b * 1024;
#pragma unroll
    for (int it = 0; it < 4; ++it)
      p[it * 256 + t] = make_float4(0.f, 0.f, 0.f, 0.f);
  } else {
    int bb = b - 128;
    int k0 = (bb >> 3) * 32, n0 = (bb & 7) * 32;
    int lr = t >> 3, lc = (t & 7) * 4;
    float4 v = *(const float4*)&B[(size_t)(k0 + lr) * HF + n0 + lc];
    tile[lr][lc] = v.x; tile[lr][lc + 1] = v.y; tile[lr][lc + 2] = v.z; tile[lr][lc + 3] = v.w;
    __syncthreads();
    ushort4 o;
    o.x = f2bf(tile[lc + 0][lr]); o.y = f2bf(tile[lc + 1][lr]);
    o.z = f2bf(tile[lc + 2][lr]); o.w = f2bf(tile[lc + 3][lr]);
    *(ushort4*)&Btbf[(size_t)(n0 + lr) * KIN + k0 + lc] = o;
  }
}

// K2: blocks 0..511 = 32x64 MFMA GEMM tiles (128 M x 4 col-tiles = 2 heads each),
//     BK=64 dbuf; A reg-staged (f32->bf16 in-kernel, swizzled ds_write), B via
//     global_load_lds (pre-swizzled source, rule #21). Wave covers one head's
//     full 32-col f-range -> in-wave el/er epilogue.
//     Blocks 512..1039 = build_adj (bitmap atomicOr).  [R15-proven best]
__global__ __launch_bounds__(256) void gemm_adj_k(const float* __restrict__ h,
                                                  const unsigned short* __restrict__ Bt,
                                                  const float* __restrict__ Wa,
                                                  unsigned short* __restrict__ gbf,
                                                  float* __restrict__ el,
                                                  float* __restrict__ er,
                                                  const int* __restrict__ ei,
                                                  const float* __restrict__ mask,
                                                  unsigned* __restrict__ bitmap) {
  __shared__ unsigned short smem[2][6144];  // per buf: A[32][64]@0, B[64][64]@2048
  const int bx = blockIdx.x, t = threadIdx.x;
  if (bx >= 512) {  // ---- build_adj: NE+NN = 135168 = 528*256 exactly ----
    int k = (bx - 512) * 256 + t;
    int s, d; float m;
    if (k < NE) { s = ei[k]; d = ei[NE + k]; m = mask[k]; }
    else        { s = k - NE; d = s; m = 1.0f; }   // diagonal forced to 1
    if (m != 0.0f) atomicOr(&bitmap[s * 128 + (d >> 5)], 1u << (d & 31));
    return;
  }
  // ---- gemm: 32x64 tile; gy*2+wc selects the head ----
  const int gx = bx & 127, gy = bx >> 7;          // 128 M-tiles x 4 col-tiles
  const int row0 = gx * 32, col0 = gy * 64;
  const int w = t >> 6, l = t & 63;
  const int wr = w >> 1, wc = w & 1;              // wave: rows wr*16..+16, cols wc*32..+32

  const int srow = t >> 3;                        // A stage: row 0..31, chunk t&7
  const int sc   = l & 7;
  const int aoff = srow * 64 + (((t & 7) ^ (srow & 7)) << 3);
  const float* gA = &h[(size_t)(row0 + srow) * KIN + (t & 7) * 8];
  // B stage: wave w, lane l -> rows (8w + l>>3) and (32 + 8w + l>>3); key (row&7) invariant +32
  const int bsrow = (w << 3) + (l >> 3);
  const int schB  = sc ^ (bsrow & 7);
  const unsigned short* gB0 = &Bt[(size_t)(col0 + bsrow) * KIN + schB * 8];
  const unsigned short* gB1 = &Bt[(size_t)(col0 + 32 + bsrow) * KIN + schB * 8];

#define BSTAGE(bf, ks)                                                                            \
  do {                                                                                            \
    __builtin_amdgcn_global_load_lds(                                                             \
        (const __attribute__((address_space(1))) unsigned int*)(gB0 + (size_t)(ks) * 64),         \
        (__attribute__((address_space(3))) unsigned int*)(&smem[bf][2048 + w * 512]), 16, 0, 0);  \
    __builtin_amdgcn_global_load_lds(                                                             \
        (const __attribute__((address_space(1))) unsigned int*)(gB1 + (size_t)(ks) * 64),         \
        (__attribute__((address_space(3))) unsigned int*)(&smem[bf][4096 + w * 512]), 16, 0, 0);  \
  } while (0)

  f32x4 acc0 = {}, acc1 = {};                     // col-frags wc*32+0..16, +16..32
  {
    float4 va0 = *(const float4*)(gA);
    float4 va1 = *(const float4*)(gA + 4);
    BSTAGE(0, 0);
    uint4 w4 = {pack2(va0.x, va0.y), pack2(va0.z, va0.w),
                pack2(va1.x, va1.y), pack2(va1.z, va1.w)};
    *(uint4*)&smem[0][aoff] = w4;
  }
  __syncthreads();

  const int lrow = l & 15, kg = l >> 4;
  const int ar  = wr * 16 + lrow;
  const int br0 = wc * 32 + lrow, br1 = wc * 32 + 16 + lrow;
  for (int ks = 0; ks < 8; ++ks) {
    const int bf = ks & 1;
    float4 na0, na1;
    if (ks < 7) {                                 // issue next-step A loads early (T14)
      na0 = *(const float4*)(gA + (ks + 1) * 64);
      na1 = *(const float4*)(gA + (ks + 1) * 64 + 4);
      BSTAGE(bf ^ 1, ks + 1);
    }
    bf16x8 a0 = *(const bf16x8*)&smem[bf][ar * 64 + ((kg ^ (ar & 7)) << 3)];
    bf16x8 a1 = *(const bf16x8*)&smem[bf][ar * 64 + (((4 + kg) ^ (ar & 7)) << 3)];
    bf16x8 b00 = *(const bf16x8*)&smem[bf][2048 + br0 * 64 + ((kg ^ (br0 & 7)) << 3)];
    bf16x8 b01 = *(const bf16x8*)&smem[bf][2048 + br0 * 64 + (((4 + kg) ^ (br0 & 7)) << 3)];
    bf16x8 b10 = *(const bf16x8*)&smem[bf][2048 + br1 * 64 + ((kg ^ (br1 & 7)) << 3)];
    bf16x8 b11 = *(const bf16x8*)&smem[bf][2048 + br1 * 64 + (((4 + kg) ^ (br1 & 7)) << 3)];
    acc0 = __builtin_amdgcn_mfma_f32_16x16x32_bf16(a0, b00, acc0, 0, 0, 0);
    acc0 = __builtin_amdgcn_mfma_f32_16x16x32_bf16(a1, b01, acc0, 0, 0, 0);
    acc1 = __builtin_amdgcn_mfma_f32_16x16x32_bf16(a0, b10, acc1, 0, 0, 0);
    acc1 = __builtin_amdgcn_mfma_f32_16x16x32_bf16(a1, b11, acc1, 0, 0, 0);
    if (ks < 7) {                                 // write-late into the other buffer
      uint4 w4 = {pack2(na0.x, na0.y), pack2(na0.z, na0.w),
                  pack2(na1.x, na1.y), pack2(na1.z, na1.w)};
      *(uint4*)&smem[bf ^ 1][aoff] = w4;
    }
    __syncthreads();
  }
#undef BSTAGE

  // C/D: col=lane&15, row=(lane>>4)*4+q  [m89-verified]
  const int crow = (l >> 4) * 4, ccol = l & 15;
  const int gr0 = row0 + wr * 16 + crow;
  const int gc0 = col0 + wc * 32 + ccol, gc1 = gc0 + 16;
#pragma unroll
  for (int q = 0; q < 4; ++q) {
    gbf[(size_t)(gr0 + q) * HF + gc0] = f2bf(acc0[q]);
    gbf[(size_t)(gr0 + q) * HF + gc1] = f2bf(acc1[q]);
  }

  // fused el/er: wave covers head (gy*2+wc)'s FULL f range: f = cfrag*16 + ccol
  const int head = (gy << 1) + wc;
  const float wal0 = Wa[ccol],      wal1 = Wa[16 + ccol];
  const float war0 = Wa[32 + ccol], war1 = Wa[48 + ccol];
#pragma unroll
  for (int q = 0; q < 4; ++q) {
    float pel = acc0[q] * wal0 + acc1[q] * wal1;
    float per = acc0[q] * war0 + acc1[q] * war1;
#pragma unroll
    for (int m = 8; m >= 1; m >>= 1) { pel += __shfl_xor(pel, m); per += __shfl_xor(per, m); }
    if (ccol == 0) {
      el[(gr0 + q) * NH + head] = pel;
      er[(gr0 + q) * NH + head] = per;
    }
  }
}

// K3: one WAVE per row, 8 rows/block (512 threads). Lane l owns output elems
// [l*4, l*4+4) (head l>>3). Wave-local bitmap expand; 4-way MLP gather loop.
__global__ __launch_bounds__(512) void attn_k(const unsigned* __restrict__ bitmap,
                                              const unsigned short* __restrict__ gbf,
                                              const float* __restrict__ el_,
                                              const float* __restrict__ er_,
                                              float* __restrict__ out) {
  __shared__ unsigned short jl[8][MAXJ];     // 4KB
  const int t = threadIdx.x, wv = t >> 6, l = t & 63;
  const int i = blockIdx.x * 8 + wv;

  unsigned w0 = bitmap[i * 128 + l];
  unsigned w1 = bitmap[i * 128 + 64 + l];
  int cnt = __popc(w0) + __popc(w1);
  int incl = cnt;
#pragma unroll
  for (int d = 1; d < 64; d <<= 1) {
    int u = __shfl_up(incl, d);
    if (l >= d) incl += u;
  }
  int total = __shfl(incl, 63);
  if (total > MAXJ) total = MAXJ;
  int off = incl - cnt;
  unsigned short* J = jl[wv];
  while (w0) {
    int b = __ffs(w0) - 1;
    if (off < MAXJ) J[off] = (unsigned short)(l * 32 + b);
    ++off; w0 &= w0 - 1;
  }
  while (w1) {
    int b = __ffs(w1) - 1;
    if (off < MAXJ) J[off] = (unsigned short)((64 + l) * 32 + b);
    ++off; w1 &= w1 - 1;
  }
  __syncthreads();

  const int hh = l >> 3;
  const float elh = el_[i * NH + hh];
  const unsigned short* gp = gbf + (size_t)l * 4;
  f32x4 accA = {}, accB = {};
  float den0 = 0.f, den1 = 0.f;
  int k = 0;
  for (; k + 4 <= total; k += 4) {           // 4-way MLP: 4 rows + 4 er in flight
    int j0 = J[k], j1 = J[k + 1], j2 = J[k + 2], j3 = J[k + 3];
    float e0 = elh + er_[j0 * NH + hh];
    float e1 = elh + er_[j1 * NH + hh];
    float e2 = elh + er_[j2 * NH + hh];
    float e3 = elh + er_[j3 * NH + hh];
    ushort4 g0 = *(const ushort4*)(gp + (size_t)j0 * HF);
    ushort4 g1 = *(const ushort4*)(gp + (size_t)j1 * HF);
    ushort4 g2 = *(const ushort4*)(gp + (size_t)j2 * HF);
    ushort4 g3 = *(const ushort4*)(gp + (size_t)j3 * HF);
    float l0 = e0 > 0.f ? e0 : SLOPE * e0;
    float l1 = e1 > 0.f ? e1 : SLOPE * e1;
    float l2 = e2 > 0.f ? e2 : SLOPE * e2;
    float l3 = e3 > 0.f ? e3 : SLOPE * e3;
    float wg0 = __expf(l0), wg1 = __expf(l1), wg2 = __expf(l2), wg3 = __expf(l3);
    den0 += wg0 + wg2; den1 += wg1 + wg3;
    accA[0] += wg0 * bf2f(g0.x); accB[0] += wg1 * bf2f(g1.x);
    accA[1] += wg0 * bf2f(g0.y); accB[1] += wg1 * bf2f(g1.y);
    accA[2] += wg0 * bf2f(g0.z); accB[2] += wg1 * bf2f(g1.z);
    accA[3] += wg0 * bf2f(g0.w); accB[3] += wg1 * bf2f(g1.w);
    accA[0] += wg2 * bf2f(g2.x); accB[0] += wg3 * bf2f(g3.x);
    accA[1] += wg2 * bf2f(g2.y); accB[1] += wg3 * bf2f(g3.y);
    accA[2] += wg2 * bf2f(g2.z); accB[2] += wg3 * bf2f(g3.z);
    accA[3] += wg2 * bf2f(g2.w); accB[3] += wg3 * bf2f(g3.w);
  }
  for (; k < total; ++k) {
    int j0 = J[k];
    float e0 = elh + er_[j0 * NH + hh];
    float l0 = e0 > 0.f ? e0 : SLOPE * e0;
    float wg0 = __expf(l0);
    ushort4 g0 = *(const ushort4*)(gp + (size_t)j0 * HF);
    den0 += wg0;
    accA[0] += wg0 * bf2f(g0.x); accA[1] += wg0 * bf2f(g0.y);
    accA[2] += wg0 * bf2f(g0.z); accA[3] += wg0 * bf2f(g0.w);
  }
  float inv = 1.f / (den0 + den1);
  float4 o = make_float4((accA[0] + accB[0]) * inv, (accA[1] + accB[1]) * inv,
                         (accA[2] + accB[2]) * inv, (accA[3] + accB[3]) * inv);
  *(float4*)&out[(size_t)i * HF + l * 4] = o;
}

extern "C" void kernel_launch(void* const* d_in, const int* in_sizes, int n_in,
                              void* d_out, int out_size, void* d_ws, size_t ws_size,
                              hipStream_t stream) {
  const float* h      = (const float*)d_in[0];
  const int*   ei     = (const int*)d_in[1];
  const float* mask   = (const float*)d_in[2];
  const float* W_fc   = (const float*)d_in[3];
  const float* W_attn = (const float*)d_in[4];
  float* out = (float*)d_out;

  char* ws = (char*)d_ws;
  unsigned* bitmap      = (unsigned*)ws;                                          // 2 MB
  unsigned short* gbf   = (unsigned short*)(ws + (size_t)2 * 1024 * 1024);        // 2 MB
  float* el             = (float*)(ws + (size_t)4 * 1024 * 1024);                 // 128 KB
  float* er             = (float*)(ws + (size_t)4 * 1024 * 1024 + 128 * 1024);    // 128 KB
  unsigned short* Btbf  = (unsigned short*)(ws + (size_t)4 * 1024 * 1024 + 256 * 1024);  // 256 KB

  prep_k<<<256, 256, 0, stream>>>(W_fc, bitmap, Btbf);
  gemm_adj_k<<<512 + 528, 256, 0, stream>>>(h, Btbf, W_attn, gbf, el, er, ei, mask, bitmap);
  attn_k<<<NN / 8, 512, 0, stream>>>(bitmap, gbf, el, er, out);
}